// Round 1
// baseline (2964.518 us; speedup 1.0000x reference)
//
#include <hip/hip_runtime.h>

// Decoder_36996848287748 — trajectory transformer, fp32 baseline.
// N=32 A=50 T=50 D=128 H=8 DH=16 L=2 FF=512 NB=32 OUT_H=512 PRED=60
// Key algebraic shortcut: social mask's ego_only row makes all agents i>0
// attend ONLY to themselves (one-hot softmax, exact in fp32) => out_i = v_i.
// Workspace use: h (40.96MB) + bias0 (2.56MB) + mask0 + flag  (~44MB total).

#define DD 128

__device__ __forceinline__ float wave_sum(float v) {
#pragma unroll
  for (int off = 32; off > 0; off >>= 1) v += __shfl_xor(v, off, 64);
  return v;
}
__device__ __forceinline__ float wave_max(float v) {
#pragma unroll
  for (int off = 32; off > 0; off >>= 1) v = fmaxf(v, __shfl_xor(v, off, 64));
  return v;
}

// invalid_entries may arrive as 1-byte bool or int32; flag=1 => bytes.
__device__ __forceinline__ bool load_inv(const void* p, int idx, int bytemode) {
  if (bytemode) return ((const unsigned char*)p)[idx] != 0;
  return ((const int*)p)[idx] != 0;
}

__global__ void detect_kernel(const void* __restrict__ inv, int* __restrict__ flag) {
  __shared__ int found;
  if (threadIdx.x == 0) found = 0;
  __syncthreads();
  const unsigned char* p = (const unsigned char*)inv;
  int loc = 0;
  for (int i = threadIdx.x; i < 16384; i += blockDim.x)
    if ((i & 3) != 0 && p[i] != 0) loc = 1;
  if (loc) atomicOr(&found, 1);
  __syncthreads();
  if (threadIdx.x == 0) *flag = found ? 1 : 0;
}

// h[tok][d] = x[tok][0:5] @ emb_W + emb_b ; 2 tokens per 256-thread block
__global__ __launch_bounds__(256) void embed_kernel(
    const float* __restrict__ x, const float* __restrict__ W,
    const float* __restrict__ b, float* __restrict__ h) {
  int tok = blockIdx.x * 2 + (threadIdx.x >> 7);
  int d = threadIdx.x & 127;
  float acc = b[d];
#pragma unroll
  for (int c = 0; c < 5; ++c) acc += x[tok * 5 + c] * W[c * DD + d];
  h[tok * DD + d] = acc;
}

// Per (n,t): ego-row social mask + per-head distance bias (only row 0 matters)
__global__ void social_prep_kernel(
    const float* __restrict__ x, const void* __restrict__ inv,
    const int* __restrict__ flagp, const float* __restrict__ dist_emb,
    float* __restrict__ bias0, int* __restrict__ mask0) {
  int nt = blockIdx.x;
  int n = nt / 50, t = nt - n * 50;
  int j = threadIdx.x;
  if (j >= 50) return;
  int bytemode = *flagp;
  float x0 = x[((n * 50 + 0) * 50 + t) * 5 + 0];
  float y0 = x[((n * 50 + 0) * 50 + t) * 5 + 1];
  float xj = x[((n * 50 + j) * 50 + t) * 5 + 0];
  float yj = x[((n * 50 + j) * 50 + t) * 5 + 1];
  float dx = x0 - xj, dy = y0 - yj;
  float dist = sqrtf(dx * dx + dy * dy);
  int bucket = (int)(dist / 1.5625f);
  bucket = bucket < 0 ? 0 : (bucket > 31 ? 31 : bucket);
  bool m;
  if (j == 0) m = false;  // diagonal forced unmasked
  else m = (dist > 50.0f) || load_inv(inv, (n * 50 + j) * 50 + t, bytemode);
  mask0[nt * 50 + j] = m ? 1 : 0;
#pragma unroll
  for (int hh = 0; hh < 8; ++hh)
    bias0[(nt * 8 + hh) * 50 + j] = dist_emb[bucket * 8 + hh];
}

// Temporal attention, fully fused per sequence (n,a): LN -> QKV -> causal
// masked softmax -> AV -> Wo -> residual.  LDS ~112KB, 1 block/CU.
__global__ __launch_bounds__(256) void temporal_attn_kernel(
    float* __restrict__ h, const void* __restrict__ inv,
    const int* __restrict__ flagp,
    const float* __restrict__ ln_g, const float* __restrict__ ln_b,
    const float* __restrict__ Wq, const float* __restrict__ Wk,
    const float* __restrict__ Wv, const float* __restrict__ Wo, int l) {
  __shared__ float hln[50][128];   // LN out; later reused as attention out
  __shared__ float qs[50][128];
  __shared__ float kt[128][53];    // K transposed, odd stride: no bank conflict
  __shared__ float vs[50][128];
  __shared__ float sc[50][53];
  __shared__ unsigned char invs[64];
  int seq = blockIdx.x;
  int tid = threadIdx.x, lane = tid & 63, wid = tid >> 6;
  const float* g  = ln_g + (l * 3 + 0) * DD;
  const float* bb = ln_b + (l * 3 + 0) * DD;
  const float* wq = Wq + (l * 2 + 0) * 16384;
  const float* wk = Wk + (l * 2 + 0) * 16384;
  const float* wvp = Wv + (l * 2 + 0) * 16384;
  const float* wo = Wo + (l * 2 + 0) * 16384;
  if (tid < 50) invs[tid] = load_inv(inv, seq * 50 + tid, *flagp) ? 1 : 0;
  // --- LayerNorm (one wave per row) ---
  for (int t = wid; t < 50; t += 4) {
    float x0 = h[(seq * 50 + t) * DD + lane];
    float x1 = h[(seq * 50 + t) * DD + lane + 64];
    float mu = wave_sum(x0 + x1) * (1.0f / 128.0f);
    float d0 = x0 - mu, d1 = x1 - mu;
    float var = wave_sum(d0 * d0 + d1 * d1) * (1.0f / 128.0f);
    float rstd = rsqrtf(var + 1e-5f);
    hln[t][lane]      = d0 * rstd * g[lane] + bb[lane];
    hln[t][lane + 64] = d1 * rstd * g[lane + 64] + bb[lane + 64];
  }
  __syncthreads();
  // --- QKV: thread owns output-dim d, accumulates 25 rows; W read once ---
  int d = tid & 127, half = tid >> 7, r0 = half * 25;
  {
    float aq[25], ak[25], av[25];
#pragma unroll
    for (int i = 0; i < 25; ++i) { aq[i] = 0.f; ak[i] = 0.f; av[i] = 0.f; }
    for (int c = 0; c < 128; c += 4) {
      float q0w = wq[(c + 0) * DD + d], q1w = wq[(c + 1) * DD + d];
      float q2w = wq[(c + 2) * DD + d], q3w = wq[(c + 3) * DD + d];
      float k0w = wk[(c + 0) * DD + d], k1w = wk[(c + 1) * DD + d];
      float k2w = wk[(c + 2) * DD + d], k3w = wk[(c + 3) * DD + d];
      float v0w = wvp[(c + 0) * DD + d], v1w = wvp[(c + 1) * DD + d];
      float v2w = wvp[(c + 2) * DD + d], v3w = wvp[(c + 3) * DD + d];
#pragma unroll
      for (int i = 0; i < 25; ++i) {
        float4 xv = *(const float4*)&hln[r0 + i][c];
        aq[i] += xv.x * q0w + xv.y * q1w + xv.z * q2w + xv.w * q3w;
        ak[i] += xv.x * k0w + xv.y * k1w + xv.z * k2w + xv.w * k3w;
        av[i] += xv.x * v0w + xv.y * v1w + xv.z * v2w + xv.w * v3w;
      }
    }
#pragma unroll
    for (int i = 0; i < 25; ++i) {
      qs[r0 + i][d] = aq[i];
      kt[d][r0 + i] = ak[i];
      vs[r0 + i][d] = av[i];
    }
  }
  __syncthreads();
  // --- per-head: scores -> softmax -> AV (attn out into hln) ---
  for (int hh = 0; hh < 8; ++hh) {
    for (int idx = tid; idx < 2500; idx += 256) {
      int tq = idx / 50, tk = idx - tq * 50;
      float s = -1e9f;
      if (!((tk > tq) || (invs[tk] && tk != tq))) {
        float acc = 0.f;
#pragma unroll
        for (int u = 0; u < 16; ++u) acc += qs[tq][hh * 16 + u] * kt[hh * 16 + u][tk];
        s = acc * 0.25f;
      }
      sc[tq][tk] = s;
    }
    __syncthreads();
    if (tid < 50) {
      float m = -1e30f;
      for (int j = 0; j < 50; ++j) m = fmaxf(m, sc[tid][j]);
      float sum = 0.f;
      for (int j = 0; j < 50; ++j) { float p = expf(sc[tid][j] - m); sc[tid][j] = p; sum += p; }
      float r = 1.f / sum;
      for (int j = 0; j < 50; ++j) sc[tid][j] *= r;
    }
    __syncthreads();
    for (int idx = tid; idx < 800; idx += 256) {
      int tq = idx >> 4, u = idx & 15;
      float acc = 0.f;
      for (int j = 0; j < 50; ++j) acc += sc[tq][j] * vs[j][hh * 16 + u];
      hln[tq][hh * 16 + u] = acc;
    }
    __syncthreads();
  }
  // --- Wo + residual ---
  {
    float acc[25];
#pragma unroll
    for (int i = 0; i < 25; ++i) acc[i] = 0.f;
    for (int c = 0; c < 128; c += 4) {
      float w0 = wo[(c + 0) * DD + d], w1 = wo[(c + 1) * DD + d];
      float w2 = wo[(c + 2) * DD + d], w3 = wo[(c + 3) * DD + d];
#pragma unroll
      for (int i = 0; i < 25; ++i) {
        float4 xv = *(const float4*)&hln[r0 + i][c];
        acc[i] += xv.x * w0 + xv.y * w1 + xv.z * w2 + xv.w * w3;
      }
    }
#pragma unroll
    for (int i = 0; i < 25; ++i)
      h[(seq * 50 + r0 + i) * DD + d] += acc[i];
  }
}

// Social attention per (n,t). Only agent-0 queries do real attention;
// agents i>0 one-hot to themselves => out_i = v_i exactly.
__global__ __launch_bounds__(256) void social_attn_kernel(
    float* __restrict__ h, const float* __restrict__ ln_g,
    const float* __restrict__ ln_b,
    const float* __restrict__ Wq, const float* __restrict__ Wk,
    const float* __restrict__ Wv, const float* __restrict__ Wo,
    const float* __restrict__ bias0, const int* __restrict__ mask0, int l) {
  __shared__ float hln[50][128];   // LN out; reused as attention out
  __shared__ float kt[128][53];
  __shared__ float vs[50][128];
  __shared__ float q0[128];
  __shared__ float aw[8][50];
  __shared__ int mrow[50];
  int nt = blockIdx.x;
  int n = nt / 50, t = nt - n * 50;
  int tid = threadIdx.x, lane = tid & 63, wid = tid >> 6;
  const float* g  = ln_g + (l * 3 + 1) * DD;
  const float* bb = ln_b + (l * 3 + 1) * DD;
  const float* wq = Wq + (l * 2 + 1) * 16384;
  const float* wk = Wk + (l * 2 + 1) * 16384;
  const float* wv = Wv + (l * 2 + 1) * 16384;
  const float* wo = Wo + (l * 2 + 1) * 16384;
  if (tid < 50) mrow[tid] = mask0[nt * 50 + tid];
  for (int j = wid; j < 50; j += 4) {
    int tok = (n * 50 + j) * 50 + t;
    float x0 = h[tok * DD + lane];
    float x1 = h[tok * DD + lane + 64];
    float mu = wave_sum(x0 + x1) * (1.0f / 128.0f);
    float d0 = x0 - mu, d1 = x1 - mu;
    float var = wave_sum(d0 * d0 + d1 * d1) * (1.0f / 128.0f);
    float rstd = rsqrtf(var + 1e-5f);
    hln[j][lane]      = d0 * rstd * g[lane] + bb[lane];
    hln[j][lane + 64] = d1 * rstd * g[lane + 64] + bb[lane + 64];
  }
  __syncthreads();
  int d = tid & 127, half = tid >> 7, r0 = half * 25;
  {
    float ak[25], av[25];
#pragma unroll
    for (int i = 0; i < 25; ++i) { ak[i] = 0.f; av[i] = 0.f; }
    for (int c = 0; c < 128; c += 4) {
      float k0w = wk[(c + 0) * DD + d], k1w = wk[(c + 1) * DD + d];
      float k2w = wk[(c + 2) * DD + d], k3w = wk[(c + 3) * DD + d];
      float v0w = wv[(c + 0) * DD + d], v1w = wv[(c + 1) * DD + d];
      float v2w = wv[(c + 2) * DD + d], v3w = wv[(c + 3) * DD + d];
#pragma unroll
      for (int i = 0; i < 25; ++i) {
        float4 xv = *(const float4*)&hln[r0 + i][c];
        ak[i] += xv.x * k0w + xv.y * k1w + xv.z * k2w + xv.w * k3w;
        av[i] += xv.x * v0w + xv.y * v1w + xv.z * v2w + xv.w * v3w;
      }
    }
#pragma unroll
    for (int i = 0; i < 25; ++i) { kt[d][r0 + i] = ak[i]; vs[r0 + i][d] = av[i]; }
  }
  if (tid < 128) {  // q for agent-0 row only
    float acc = 0.f;
    for (int c = 0; c < 128; c += 4) {
      float4 xv = *(const float4*)&hln[0][c];
      acc += xv.x * wq[(c + 0) * DD + tid] + xv.y * wq[(c + 1) * DD + tid] +
             xv.z * wq[(c + 2) * DD + tid] + xv.w * wq[(c + 3) * DD + tid];
    }
    q0[tid] = acc;
  }
  __syncthreads();
  // softmax weights for the 8 heads (wave 0)
  if (wid == 0) {
#pragma unroll
    for (int hh = 0; hh < 8; ++hh) {
      float s = -1e30f;
      if (lane < 50) {
        if (mrow[lane]) s = -1e9f;
        else {
          float acc = 0.f;
#pragma unroll
          for (int u = 0; u < 16; ++u) acc += q0[hh * 16 + u] * kt[hh * 16 + u][lane];
          s = acc * 0.25f + bias0[(nt * 8 + hh) * 50 + lane];
        }
      }
      float m = wave_max(s);
      float p = (lane < 50) ? expf(s - m) : 0.f;
      float ssum = wave_sum(p);
      if (lane < 50) aw[hh][lane] = p / ssum;
    }
  }
  __syncthreads();
  // attention out into hln: rows >0 copy v, row 0 = aw @ v
  for (int idx = tid; idx < 6400; idx += 256) {
    int j = idx >> 7, dd = idx & 127;
    if (j > 0) hln[j][dd] = vs[j][dd];
  }
  if (tid < 128) {
    int hh = tid >> 4;
    float acc = 0.f;
    for (int j = 0; j < 50; ++j) acc += aw[hh][j] * vs[j][tid];
    hln[0][tid] = acc;
  }
  __syncthreads();
  // Wo + residual (strided tokens)
  {
    float acc[25];
#pragma unroll
    for (int i = 0; i < 25; ++i) acc[i] = 0.f;
    for (int c = 0; c < 128; c += 4) {
      float w0 = wo[(c + 0) * DD + d], w1 = wo[(c + 1) * DD + d];
      float w2 = wo[(c + 2) * DD + d], w3 = wo[(c + 3) * DD + d];
#pragma unroll
      for (int i = 0; i < 25; ++i) {
        float4 xv = *(const float4*)&hln[r0 + i][c];
        acc[i] += xv.x * w0 + xv.y * w1 + xv.z * w2 + xv.w * w3;
      }
    }
#pragma unroll
    for (int i = 0; i < 25; ++i) {
      int tok = (n * 50 + (r0 + i)) * 50 + t;
      h[tok * DD + d] += acc[i];
    }
  }
}

// FFN: 16 tokens/block, LN -> W1+ReLU -> W2 -> residual
__global__ __launch_bounds__(256) void ffn_kernel(
    float* __restrict__ h, const float* __restrict__ ln_g,
    const float* __restrict__ ln_b,
    const float* __restrict__ W1, const float* __restrict__ b1p,
    const float* __restrict__ W2, const float* __restrict__ b2p, int l) {
  __shared__ float xln[16][128];
  __shared__ float hid[16][512];
  int base = blockIdx.x * 16;
  int tid = threadIdx.x, lane = tid & 63, wid = tid >> 6;
  const float* g  = ln_g + (l * 3 + 2) * DD;
  const float* bb = ln_b + (l * 3 + 2) * DD;
  const float* w1 = W1 + l * 65536;
  const float* b1 = b1p + l * 512;
  const float* w2 = W2 + l * 65536;
  const float* b2 = b2p + l * 128;
  for (int r = wid; r < 16; r += 4) {
    int tok = base + r;
    float x0 = h[tok * DD + lane], x1 = h[tok * DD + lane + 64];
    float mu = wave_sum(x0 + x1) * (1.0f / 128.0f);
    float d0 = x0 - mu, d1 = x1 - mu;
    float var = wave_sum(d0 * d0 + d1 * d1) * (1.0f / 128.0f);
    float rstd = rsqrtf(var + 1e-5f);
    xln[r][lane]      = d0 * rstd * g[lane] + bb[lane];
    xln[r][lane + 64] = d1 * rstd * g[lane + 64] + bb[lane + 64];
  }
  __syncthreads();
  {
    int f = tid;
    float a0[16], a1[16];
#pragma unroll
    for (int r = 0; r < 16; ++r) { a0[r] = 0.f; a1[r] = 0.f; }
    for (int c = 0; c < 128; c += 4) {
      float w00 = w1[(c + 0) * 512 + f], w01 = w1[(c + 1) * 512 + f];
      float w02 = w1[(c + 2) * 512 + f], w03 = w1[(c + 3) * 512 + f];
      float w10 = w1[(c + 0) * 512 + f + 256], w11 = w1[(c + 1) * 512 + f + 256];
      float w12 = w1[(c + 2) * 512 + f + 256], w13 = w1[(c + 3) * 512 + f + 256];
#pragma unroll
      for (int r = 0; r < 16; ++r) {
        float4 xv = *(const float4*)&xln[r][c];
        a0[r] += xv.x * w00 + xv.y * w01 + xv.z * w02 + xv.w * w03;
        a1[r] += xv.x * w10 + xv.y * w11 + xv.z * w12 + xv.w * w13;
      }
    }
    float bb0 = b1[f], bb1 = b1[f + 256];
#pragma unroll
    for (int r = 0; r < 16; ++r) {
      hid[r][f]       = fmaxf(a0[r] + bb0, 0.f);
      hid[r][f + 256] = fmaxf(a1[r] + bb1, 0.f);
    }
  }
  __syncthreads();
  {
    int dd = tid & 127, rbase = (tid >> 7) * 8;
    float acc[8];
#pragma unroll
    for (int r = 0; r < 8; ++r) acc[r] = 0.f;
    for (int f2 = 0; f2 < 512; f2 += 4) {
      float wv0 = w2[(f2 + 0) * DD + dd], wv1 = w2[(f2 + 1) * DD + dd];
      float wv2 = w2[(f2 + 2) * DD + dd], wv3 = w2[(f2 + 3) * DD + dd];
#pragma unroll
      for (int r = 0; r < 8; ++r) {
        float4 hv = *(const float4*)&hid[rbase + r][f2];
        acc[r] += hv.x * wv0 + hv.y * wv1 + hv.z * wv2 + hv.w * wv3;
      }
    }
    float bv = b2[dd];
#pragma unroll
    for (int r = 0; r < 8; ++r) h[(base + rbase + r) * DD + dd] += acc[r] + bv;
  }
}

// Final ego MLP: e = (h[:,0] @ W1 + b1) @ W2 + b2 -> out (N*T,120)
__global__ __launch_bounds__(256) void ego_mlp_kernel(
    const float* __restrict__ h, const float* __restrict__ W1,
    const float* __restrict__ b1, const float* __restrict__ W2,
    const float* __restrict__ b2, float* __restrict__ out) {
  __shared__ float xr[8][128];
  __shared__ float mid[8][512];
  int base = blockIdx.x * 8;  // nt base
  int tid = threadIdx.x;
  for (int idx = tid; idx < 1024; idx += 256) {
    int r = idx >> 7, dd = idx & 127;
    int nt = base + r, n = nt / 50, t = nt - n * 50;
    xr[r][dd] = h[(n * 2500 + t) * DD + dd];
  }
  __syncthreads();
  {
    int f = tid;
    float a0[8], a1[8];
#pragma unroll
    for (int r = 0; r < 8; ++r) { a0[r] = b1[f]; a1[r] = b1[f + 256]; }
    for (int c = 0; c < 128; ++c) {
      float w0 = W1[c * 512 + f], w1 = W1[c * 512 + f + 256];
#pragma unroll
      for (int r = 0; r < 8; ++r) {
        float xv = xr[r][c];
        a0[r] += xv * w0;
        a1[r] += xv * w1;
      }
    }
#pragma unroll
    for (int r = 0; r < 8; ++r) { mid[r][f] = a0[r]; mid[r][f + 256] = a1[r]; }
  }
  __syncthreads();
  for (int idx = tid; idx < 960; idx += 256) {
    int r = idx / 120, p = idx - r * 120;
    float acc = b2[p];
    for (int f2 = 0; f2 < 512; ++f2) acc += mid[r][f2] * W2[f2 * 120 + p];
    out[(base + r) * 120 + p] = acc;
  }
}

extern "C" void kernel_launch(void* const* d_in, const int* in_sizes, int n_in,
                              void* d_out, int out_size, void* d_ws, size_t ws_size,
                              hipStream_t stream) {
  const float* x        = (const float*)d_in[0];
  const void*  inv      = d_in[1];
  const float* emb_W    = (const float*)d_in[2];
  const float* emb_b    = (const float*)d_in[3];
  const float* dist_emb = (const float*)d_in[4];
  const float* ln_g     = (const float*)d_in[5];
  const float* ln_b     = (const float*)d_in[6];
  const float* Wq       = (const float*)d_in[7];
  const float* Wk       = (const float*)d_in[8];
  const float* Wv       = (const float*)d_in[9];
  const float* Wo       = (const float*)d_in[10];
  const float* ffn_W1   = (const float*)d_in[11];
  const float* ffn_b1   = (const float*)d_in[12];
  const float* ffn_W2   = (const float*)d_in[13];
  const float* ffn_b2   = (const float*)d_in[14];
  const float* mlp_W1   = (const float*)d_in[15];
  const float* mlp_b1   = (const float*)d_in[16];
  const float* mlp_W2   = (const float*)d_in[17];
  const float* mlp_b2   = (const float*)d_in[18];
  float* out = (float*)d_out;

  float* ws    = (float*)d_ws;
  float* h     = ws;                      // 80000*128
  float* bias0 = ws + 10240000;           // 1600*8*50
  int*   mask0 = (int*)(ws + 10880000);   // 1600*50
  int*   flag  = (int*)(ws + 10960000);   // 1

  detect_kernel<<<dim3(1), dim3(256), 0, stream>>>(inv, flag);
  embed_kernel<<<dim3(40000), dim3(256), 0, stream>>>(x, emb_W, emb_b, h);
  social_prep_kernel<<<dim3(1600), dim3(64), 0, stream>>>(x, inv, flag, dist_emb,
                                                          bias0, mask0);
  for (int l = 0; l < 2; ++l) {
    temporal_attn_kernel<<<dim3(1600), dim3(256), 0, stream>>>(
        h, inv, flag, ln_g, ln_b, Wq, Wk, Wv, Wo, l);
    social_attn_kernel<<<dim3(1600), dim3(256), 0, stream>>>(
        h, ln_g, ln_b, Wq, Wk, Wv, Wo, bias0, mask0, l);
    ffn_kernel<<<dim3(5000), dim3(256), 0, stream>>>(
        h, ln_g, ln_b, ffn_W1, ffn_b1, ffn_W2, ffn_b2, l);
  }
  ego_mlp_kernel<<<dim3(200), dim3(256), 0, stream>>>(h, mlp_W1, mlp_b1,
                                                      mlp_W2, mlp_b2, out);
}

// Round 2
// 2158.675 us; speedup vs baseline: 1.3733x; 1.3733x over previous
//
#include <hip/hip_runtime.h>

// Decoder_36996848287748 — trajectory transformer, fp32, v2.
// N=32 A=50 T=50 D=128 H=8 DH=16 L=2 FF=512 NB=32 OUT_H=512 PRED=60
// v2: temporal/social attention rebuilt for occupancy: 512 thr/block,
// LDS <80KB (2 blocks/CU), online-softmax with one thread per (head,row),
// Q overlaid on dead LN buffer via union. All LDS reads broadcast/unit-stride.

#define DD 128

__device__ __forceinline__ float wave_sum(float v) {
#pragma unroll
  for (int off = 32; off > 0; off >>= 1) v += __shfl_xor(v, off, 64);
  return v;
}
__device__ __forceinline__ float wave_max(float v) {
#pragma unroll
  for (int off = 32; off > 0; off >>= 1) v = fmaxf(v, __shfl_xor(v, off, 64));
  return v;
}

// invalid_entries may arrive as 1-byte bool or int32; flag=1 => bytes.
__device__ __forceinline__ bool load_inv(const void* p, int idx, int bytemode) {
  if (bytemode) return ((const unsigned char*)p)[idx] != 0;
  return ((const int*)p)[idx] != 0;
}

__global__ void detect_kernel(const void* __restrict__ inv, int* __restrict__ flag) {
  __shared__ int found;
  if (threadIdx.x == 0) found = 0;
  __syncthreads();
  const unsigned char* p = (const unsigned char*)inv;
  int loc = 0;
  for (int i = threadIdx.x; i < 16384; i += blockDim.x)
    if ((i & 3) != 0 && p[i] != 0) loc = 1;
  if (loc) atomicOr(&found, 1);
  __syncthreads();
  if (threadIdx.x == 0) *flag = found ? 1 : 0;
}

__global__ __launch_bounds__(256) void embed_kernel(
    const float* __restrict__ x, const float* __restrict__ W,
    const float* __restrict__ b, float* __restrict__ h) {
  int tok = blockIdx.x * 2 + (threadIdx.x >> 7);
  int d = threadIdx.x & 127;
  float acc = b[d];
#pragma unroll
  for (int c = 0; c < 5; ++c) acc += x[tok * 5 + c] * W[c * DD + d];
  h[tok * DD + d] = acc;
}

__global__ void social_prep_kernel(
    const float* __restrict__ x, const void* __restrict__ inv,
    const int* __restrict__ flagp, const float* __restrict__ dist_emb,
    float* __restrict__ bias0, int* __restrict__ mask0) {
  int nt = blockIdx.x;
  int n = nt / 50, t = nt - n * 50;
  int j = threadIdx.x;
  if (j >= 50) return;
  int bytemode = *flagp;
  float x0 = x[((n * 50 + 0) * 50 + t) * 5 + 0];
  float y0 = x[((n * 50 + 0) * 50 + t) * 5 + 1];
  float xj = x[((n * 50 + j) * 50 + t) * 5 + 0];
  float yj = x[((n * 50 + j) * 50 + t) * 5 + 1];
  float dx = x0 - xj, dy = y0 - yj;
  float dist = sqrtf(dx * dx + dy * dy);
  int bucket = (int)(dist / 1.5625f);
  bucket = bucket < 0 ? 0 : (bucket > 31 ? 31 : bucket);
  bool m;
  if (j == 0) m = false;
  else m = (dist > 50.0f) || load_inv(inv, (n * 50 + j) * 50 + t, bytemode);
  mask0[nt * 50 + j] = m ? 1 : 0;
#pragma unroll
  for (int hh = 0; hh < 8; ++hh)
    bias0[(nt * 8 + hh) * 50 + j] = dist_emb[bucket * 8 + hh];
}

// ---------------- Temporal attention v2 ----------------
// 512 threads. LDS = union(26,624) + ks 25,600 + vs 25,600 + 64 = 77,888 B
// => 2 blocks/CU, 16 waves/CU.
__global__ __launch_bounds__(512, 4) void temporal_attn_kernel(
    float* __restrict__ h, const void* __restrict__ inv,
    const int* __restrict__ flagp,
    const float* __restrict__ ln_g, const float* __restrict__ ln_b,
    const float* __restrict__ Wq, const float* __restrict__ Wk,
    const float* __restrict__ Wv, const float* __restrict__ Wo, int l) {
  __shared__ union {
    float hln[50][128];   // phase 1-2: LN output
    float qsT[128][52];   // phase 3: Q transposed (stride-1 lane reads)
    float att[50][128];   // phase 3b-4: attention output
  } u;
  __shared__ float ks[50][128];
  __shared__ float vs[50][128];
  __shared__ unsigned char invs[64];
  int seq = blockIdx.x;
  int tid = threadIdx.x, lane = tid & 63, wid = tid >> 6;
  const float* g  = ln_g + (l * 3 + 0) * DD;
  const float* bb = ln_b + (l * 3 + 0) * DD;
  const float* wq = Wq + (l * 2 + 0) * 16384;
  const float* wk = Wk + (l * 2 + 0) * 16384;
  const float* wvp = Wv + (l * 2 + 0) * 16384;
  const float* wo = Wo + (l * 2 + 0) * 16384;
  if (tid < 50) invs[tid] = load_inv(inv, seq * 50 + tid, *flagp) ? 1 : 0;
  // --- P1: LayerNorm, one wave per row, 8 waves ---
  for (int t = wid; t < 50; t += 8) {
    float x0 = h[(seq * 50 + t) * DD + lane];
    float x1 = h[(seq * 50 + t) * DD + lane + 64];
    float mu = wave_sum(x0 + x1) * (1.0f / 128.0f);
    float d0 = x0 - mu, d1 = x1 - mu;
    float var = wave_sum(d0 * d0 + d1 * d1) * (1.0f / 128.0f);
    float rstd = rsqrtf(var + 1e-5f);
    u.hln[t][lane]      = d0 * rstd * g[lane] + bb[lane];
    u.hln[t][lane + 64] = d1 * rstd * g[lane + 64] + bb[lane + 64];
  }
  __syncthreads();
  // --- P2: QKV into registers; thread owns dim d, rows rg,rg+4,... ---
  int d = tid & 127, rg = tid >> 7;
  {
    float aq[13], ak[13], av[13];
#pragma unroll
    for (int i = 0; i < 13; ++i) { aq[i] = 0.f; ak[i] = 0.f; av[i] = 0.f; }
    for (int c = 0; c < 128; c += 4) {
      float q0w = wq[(c + 0) * DD + d], q1w = wq[(c + 1) * DD + d];
      float q2w = wq[(c + 2) * DD + d], q3w = wq[(c + 3) * DD + d];
      float k0w = wk[(c + 0) * DD + d], k1w = wk[(c + 1) * DD + d];
      float k2w = wk[(c + 2) * DD + d], k3w = wk[(c + 3) * DD + d];
      float v0w = wvp[(c + 0) * DD + d], v1w = wvp[(c + 1) * DD + d];
      float v2w = wvp[(c + 2) * DD + d], v3w = wvp[(c + 3) * DD + d];
#pragma unroll
      for (int i = 0; i < 13; ++i) {
        int r = rg + 4 * i;
        if (r < 50) {
          float4 xv = *(const float4*)&u.hln[r][c];
          aq[i] += xv.x * q0w + xv.y * q1w + xv.z * q2w + xv.w * q3w;
          ak[i] += xv.x * k0w + xv.y * k1w + xv.z * k2w + xv.w * k3w;
          av[i] += xv.x * v0w + xv.y * v1w + xv.z * v2w + xv.w * v3w;
        }
      }
    }
#pragma unroll
    for (int i = 0; i < 13; ++i) {
      int r = rg + 4 * i;
      if (r < 50) { ks[r][d] = ak[i]; vs[r][d] = av[i]; }
    }
    __syncthreads();  // all hln reads done -> safe to overlay qsT
#pragma unroll
    for (int i = 0; i < 13; ++i) {
      int r = rg + 4 * i;
      if (r < 50) u.qsT[d][r] = aq[i];
    }
  }
  __syncthreads();
  // --- P3: attention, one thread per (head, q-row); online softmax ---
  bool act = tid < 400;
  int hh = tid / 50;
  int tq = tid - hh * 50;
  float q[16], o[16];
  float mx = -1e30f, ssum = 0.f;
  if (act) {
#pragma unroll
    for (int u2 = 0; u2 < 16; ++u2) q[u2] = u.qsT[hh * 16 + u2][tq];
  }
  __syncthreads();  // q reads complete before att overlays the union
  if (act) {
    // pass 1: online max + sum
    for (int tk = 0; tk < 50; ++tk) {
      bool msk = (tk > tq) || (invs[tk] && tk != tq);
      float acc = 0.f;
#pragma unroll
      for (int u2 = 0; u2 < 16; u2 += 4) {
        float4 kv = *(const float4*)&ks[tk][hh * 16 + u2];
        acc += q[u2] * kv.x + q[u2 + 1] * kv.y + q[u2 + 2] * kv.z + q[u2 + 3] * kv.w;
      }
      float s = msk ? -1e9f : acc * 0.25f;
      float nm = fmaxf(mx, s);
      ssum = ssum * expf(mx - nm) + expf(s - nm);
      mx = nm;
    }
#pragma unroll
    for (int u2 = 0; u2 < 16; ++u2) o[u2] = 0.f;
    // pass 2: recompute scores, accumulate AV
    for (int tk = 0; tk < 50; ++tk) {
      bool msk = (tk > tq) || (invs[tk] && tk != tq);
      float acc = 0.f;
#pragma unroll
      for (int u2 = 0; u2 < 16; u2 += 4) {
        float4 kv = *(const float4*)&ks[tk][hh * 16 + u2];
        acc += q[u2] * kv.x + q[u2 + 1] * kv.y + q[u2 + 2] * kv.z + q[u2 + 3] * kv.w;
      }
      float s = msk ? -1e9f : acc * 0.25f;
      float p = expf(s - mx);
#pragma unroll
      for (int u2 = 0; u2 < 16; u2 += 4) {
        float4 vv = *(const float4*)&vs[tk][hh * 16 + u2];
        o[u2] += p * vv.x; o[u2 + 1] += p * vv.y;
        o[u2 + 2] += p * vv.z; o[u2 + 3] += p * vv.w;
      }
    }
    float rs = 1.f / ssum;
#pragma unroll
    for (int u2 = 0; u2 < 16; u2 += 4) {
      *(float4*)&u.att[tq][hh * 16 + u2] =
          make_float4(o[u2] * rs, o[u2 + 1] * rs, o[u2 + 2] * rs, o[u2 + 3] * rs);
    }
  }
  __syncthreads();
  // --- P4: Wo + residual ---
  {
    float acc[13];
#pragma unroll
    for (int i = 0; i < 13; ++i) acc[i] = 0.f;
    for (int c = 0; c < 128; c += 4) {
      float w0 = wo[(c + 0) * DD + d], w1 = wo[(c + 1) * DD + d];
      float w2 = wo[(c + 2) * DD + d], w3 = wo[(c + 3) * DD + d];
#pragma unroll
      for (int i = 0; i < 13; ++i) {
        int r = rg + 4 * i;
        if (r < 50) {
          float4 xv = *(const float4*)&u.att[r][c];
          acc[i] += xv.x * w0 + xv.y * w1 + xv.z * w2 + xv.w * w3;
        }
      }
    }
#pragma unroll
    for (int i = 0; i < 13; ++i) {
      int r = rg + 4 * i;
      if (r < 50) h[(seq * 50 + r) * DD + d] += acc[i];
    }
  }
}

// ---------------- Social attention v2 ----------------
// Only agent-0 queries attend; rows i>0 one-hot to self => out_i = v_i.
// 512 threads. LDS = 25,600+26,624+25,600+512+512+1,600 = 80,448 B => 2/CU.
__global__ __launch_bounds__(512, 4) void social_attn_kernel(
    float* __restrict__ h, const float* __restrict__ ln_g,
    const float* __restrict__ ln_b,
    const float* __restrict__ Wq, const float* __restrict__ Wk,
    const float* __restrict__ Wv, const float* __restrict__ Wo,
    const float* __restrict__ bias0, const int* __restrict__ mask0, int l) {
  __shared__ float hln[50][128];
  __shared__ float kt[128][52];   // K transposed (lane-varying tk reads)
  __shared__ float vs[50][128];
  __shared__ float q0s[128];
  __shared__ float attn0[128];
  __shared__ float aw[8][50];
  int nt = blockIdx.x;
  int n = nt / 50, t = nt - n * 50;
  int tid = threadIdx.x, lane = tid & 63, wid = tid >> 6;
  const float* g  = ln_g + (l * 3 + 1) * DD;
  const float* bb = ln_b + (l * 3 + 1) * DD;
  const float* wq = Wq + (l * 2 + 1) * 16384;
  const float* wk = Wk + (l * 2 + 1) * 16384;
  const float* wv = Wv + (l * 2 + 1) * 16384;
  const float* wo = Wo + (l * 2 + 1) * 16384;
  // --- P1: LayerNorm over strided tokens ---
  for (int j = wid; j < 50; j += 8) {
    int tok = (n * 50 + j) * 50 + t;
    float x0 = h[tok * DD + lane];
    float x1 = h[tok * DD + lane + 64];
    float mu = wave_sum(x0 + x1) * (1.0f / 128.0f);
    float d0 = x0 - mu, d1 = x1 - mu;
    float var = wave_sum(d0 * d0 + d1 * d1) * (1.0f / 128.0f);
    float rstd = rsqrtf(var + 1e-5f);
    hln[j][lane]      = d0 * rstd * g[lane] + bb[lane];
    hln[j][lane + 64] = d1 * rstd * g[lane + 64] + bb[lane + 64];
  }
  __syncthreads();
  // --- P2: K,V for all rows; q0 (agent 0) on rowgroup 3 ---
  int d = tid & 127, rg = tid >> 7;
  {
    float ak[13], av[13], q0a = 0.f;
#pragma unroll
    for (int i = 0; i < 13; ++i) { ak[i] = 0.f; av[i] = 0.f; }
    for (int c = 0; c < 128; c += 4) {
      float k0w = wk[(c + 0) * DD + d], k1w = wk[(c + 1) * DD + d];
      float k2w = wk[(c + 2) * DD + d], k3w = wk[(c + 3) * DD + d];
      float v0w = wv[(c + 0) * DD + d], v1w = wv[(c + 1) * DD + d];
      float v2w = wv[(c + 2) * DD + d], v3w = wv[(c + 3) * DD + d];
#pragma unroll
      for (int i = 0; i < 13; ++i) {
        int r = rg + 4 * i;
        if (r < 50) {
          float4 xv = *(const float4*)&hln[r][c];
          ak[i] += xv.x * k0w + xv.y * k1w + xv.z * k2w + xv.w * k3w;
          av[i] += xv.x * v0w + xv.y * v1w + xv.z * v2w + xv.w * v3w;
        }
      }
      if (rg == 3) {
        float4 xv = *(const float4*)&hln[0][c];
        q0a += xv.x * wq[(c + 0) * DD + d] + xv.y * wq[(c + 1) * DD + d] +
               xv.z * wq[(c + 2) * DD + d] + xv.w * wq[(c + 3) * DD + d];
      }
    }
#pragma unroll
    for (int i = 0; i < 13; ++i) {
      int r = rg + 4 * i;
      if (r < 50) { kt[d][r] = ak[i]; vs[r][d] = av[i]; }
    }
    if (rg == 3) q0s[d] = q0a;
  }
  __syncthreads();
  // --- P3: masked softmax, one wave per head ---
  {
    int hh = wid;
    float s = -1e30f;
    if (lane < 50) {
      int mk = mask0[nt * 50 + lane];
      float acc = 0.f;
#pragma unroll
      for (int u2 = 0; u2 < 16; ++u2)
        acc += q0s[hh * 16 + u2] * kt[hh * 16 + u2][lane];
      s = mk ? -1e9f : acc * 0.25f + bias0[(nt * 8 + hh) * 50 + lane];
    }
    float m = wave_max(s);
    float p = (lane < 50) ? expf(s - m) : 0.f;
    float sm = wave_sum(p);
    if (lane < 50) aw[hh][lane] = p / sm;
  }
  __syncthreads();
  // --- P3b: row-0 AV ---
  if (tid < 128) {
    int hh2 = tid >> 4;
    float acc = 0.f;
    for (int j = 0; j < 50; ++j) acc += aw[hh2][j] * vs[j][tid];
    attn0[tid] = acc;
  }
  __syncthreads();
  // --- P4: Wo + residual; attn-out row r>0 is vs[r] ---
  {
    float acc[13];
#pragma unroll
    for (int i = 0; i < 13; ++i) acc[i] = 0.f;
    for (int c = 0; c < 128; c += 4) {
      float w0 = wo[(c + 0) * DD + d], w1 = wo[(c + 1) * DD + d];
      float w2 = wo[(c + 2) * DD + d], w3 = wo[(c + 3) * DD + d];
#pragma unroll
      for (int i = 0; i < 13; ++i) {
        int r = rg + 4 * i;
        if (r < 50) {
          const float* src = (r == 0) ? &attn0[0] : &vs[r][0];
          float4 xv = *(const float4*)&src[c];
          acc[i] += xv.x * w0 + xv.y * w1 + xv.z * w2 + xv.w * w3;
        }
      }
    }
#pragma unroll
    for (int i = 0; i < 13; ++i) {
      int r = rg + 4 * i;
      if (r < 50) {
        int tok = (n * 50 + r) * 50 + t;
        h[tok * DD + d] += acc[i];
      }
    }
  }
}

// FFN: 16 tokens/block, LN -> W1+ReLU -> W2 -> residual
__global__ __launch_bounds__(256) void ffn_kernel(
    float* __restrict__ h, const float* __restrict__ ln_g,
    const float* __restrict__ ln_b,
    const float* __restrict__ W1, const float* __restrict__ b1p,
    const float* __restrict__ W2, const float* __restrict__ b2p, int l) {
  __shared__ float xln[16][128];
  __shared__ float hid[16][512];
  int base = blockIdx.x * 16;
  int tid = threadIdx.x, lane = tid & 63, wid = tid >> 6;
  const float* g  = ln_g + (l * 3 + 2) * DD;
  const float* bb = ln_b + (l * 3 + 2) * DD;
  const float* w1 = W1 + l * 65536;
  const float* b1 = b1p + l * 512;
  const float* w2 = W2 + l * 65536;
  const float* b2 = b2p + l * 128;
  for (int r = wid; r < 16; r += 4) {
    int tok = base + r;
    float x0 = h[tok * DD + lane], x1 = h[tok * DD + lane + 64];
    float mu = wave_sum(x0 + x1) * (1.0f / 128.0f);
    float d0 = x0 - mu, d1 = x1 - mu;
    float var = wave_sum(d0 * d0 + d1 * d1) * (1.0f / 128.0f);
    float rstd = rsqrtf(var + 1e-5f);
    xln[r][lane]      = d0 * rstd * g[lane] + bb[lane];
    xln[r][lane + 64] = d1 * rstd * g[lane + 64] + bb[lane + 64];
  }
  __syncthreads();
  {
    int f = tid;
    float a0[16], a1[16];
#pragma unroll
    for (int r = 0; r < 16; ++r) { a0[r] = 0.f; a1[r] = 0.f; }
    for (int c = 0; c < 128; c += 4) {
      float w00 = w1[(c + 0) * 512 + f], w01 = w1[(c + 1) * 512 + f];
      float w02 = w1[(c + 2) * 512 + f], w03 = w1[(c + 3) * 512 + f];
      float w10 = w1[(c + 0) * 512 + f + 256], w11 = w1[(c + 1) * 512 + f + 256];
      float w12 = w1[(c + 2) * 512 + f + 256], w13 = w1[(c + 3) * 512 + f + 256];
#pragma unroll
      for (int r = 0; r < 16; ++r) {
        float4 xv = *(const float4*)&xln[r][c];
        a0[r] += xv.x * w00 + xv.y * w01 + xv.z * w02 + xv.w * w03;
        a1[r] += xv.x * w10 + xv.y * w11 + xv.z * w12 + xv.w * w13;
      }
    }
    float bb0 = b1[f], bb1 = b1[f + 256];
#pragma unroll
    for (int r = 0; r < 16; ++r) {
      hid[r][f]       = fmaxf(a0[r] + bb0, 0.f);
      hid[r][f + 256] = fmaxf(a1[r] + bb1, 0.f);
    }
  }
  __syncthreads();
  {
    int dd = tid & 127, rbase = (tid >> 7) * 8;
    float acc[8];
#pragma unroll
    for (int r = 0; r < 8; ++r) acc[r] = 0.f;
    for (int f2 = 0; f2 < 512; f2 += 4) {
      float wv0 = w2[(f2 + 0) * DD + dd], wv1 = w2[(f2 + 1) * DD + dd];
      float wv2 = w2[(f2 + 2) * DD + dd], wv3 = w2[(f2 + 3) * DD + dd];
#pragma unroll
      for (int r = 0; r < 8; ++r) {
        float4 hv = *(const float4*)&hid[rbase + r][f2];
        acc[r] += hv.x * wv0 + hv.y * wv1 + hv.z * wv2 + hv.w * wv3;
      }
    }
    float bv = b2[dd];
#pragma unroll
    for (int r = 0; r < 8; ++r) h[(base + rbase + r) * DD + dd] += acc[r] + bv;
  }
}

// Final ego MLP: e = (h[:,0] @ W1 + b1) @ W2 + b2 -> out (N*T,120)
__global__ __launch_bounds__(256) void ego_mlp_kernel(
    const float* __restrict__ h, const float* __restrict__ W1,
    const float* __restrict__ b1, const float* __restrict__ W2,
    const float* __restrict__ b2, float* __restrict__ out) {
  __shared__ float xr[8][128];
  __shared__ float mid[8][512];
  int base = blockIdx.x * 8;
  int tid = threadIdx.x;
  for (int idx = tid; idx < 1024; idx += 256) {
    int r = idx >> 7, dd = idx & 127;
    int nt = base + r, n = nt / 50, t = nt - n * 50;
    xr[r][dd] = h[(n * 2500 + t) * DD + dd];
  }
  __syncthreads();
  {
    int f = tid;
    float a0[8], a1[8];
#pragma unroll
    for (int r = 0; r < 8; ++r) { a0[r] = b1[f]; a1[r] = b1[f + 256]; }
    for (int c = 0; c < 128; ++c) {
      float w0 = W1[c * 512 + f], w1 = W1[c * 512 + f + 256];
#pragma unroll
      for (int r = 0; r < 8; ++r) {
        float xv = xr[r][c];
        a0[r] += xv * w0;
        a1[r] += xv * w1;
      }
    }
#pragma unroll
    for (int r = 0; r < 8; ++r) { mid[r][f] = a0[r]; mid[r][f + 256] = a1[r]; }
  }
  __syncthreads();
  for (int idx = tid; idx < 960; idx += 256) {
    int r = idx / 120, p = idx - r * 120;
    float acc = b2[p];
    for (int f2 = 0; f2 < 512; ++f2) acc += mid[r][f2] * W2[f2 * 120 + p];
    out[(base + r) * 120 + p] = acc;
  }
}

extern "C" void kernel_launch(void* const* d_in, const int* in_sizes, int n_in,
                              void* d_out, int out_size, void* d_ws, size_t ws_size,
                              hipStream_t stream) {
  const float* x        = (const float*)d_in[0];
  const void*  inv      = d_in[1];
  const float* emb_W    = (const float*)d_in[2];
  const float* emb_b    = (const float*)d_in[3];
  const float* dist_emb = (const float*)d_in[4];
  const float* ln_g     = (const float*)d_in[5];
  const float* ln_b     = (const float*)d_in[6];
  const float* Wq       = (const float*)d_in[7];
  const float* Wk       = (const float*)d_in[8];
  const float* Wv       = (const float*)d_in[9];
  const float* Wo       = (const float*)d_in[10];
  const float* ffn_W1   = (const float*)d_in[11];
  const float* ffn_b1   = (const float*)d_in[12];
  const float* ffn_W2   = (const float*)d_in[13];
  const float* ffn_b2   = (const float*)d_in[14];
  const float* mlp_W1   = (const float*)d_in[15];
  const float* mlp_b1   = (const float*)d_in[16];
  const float* mlp_W2   = (const float*)d_in[17];
  const float* mlp_b2   = (const float*)d_in[18];
  float* out = (float*)d_out;

  float* ws    = (float*)d_ws;
  float* h     = ws;                      // 80000*128
  float* bias0 = ws + 10240000;           // 1600*8*50
  int*   mask0 = (int*)(ws + 10880000);   // 1600*50
  int*   flag  = (int*)(ws + 10960000);   // 1

  detect_kernel<<<dim3(1), dim3(256), 0, stream>>>(inv, flag);
  embed_kernel<<<dim3(40000), dim3(256), 0, stream>>>(x, emb_W, emb_b, h);
  social_prep_kernel<<<dim3(1600), dim3(64), 0, stream>>>(x, inv, flag, dist_emb,
                                                          bias0, mask0);
  for (int l = 0; l < 2; ++l) {
    temporal_attn_kernel<<<dim3(1600), dim3(512), 0, stream>>>(
        h, inv, flag, ln_g, ln_b, Wq, Wk, Wv, Wo, l);
    social_attn_kernel<<<dim3(1600), dim3(512), 0, stream>>>(
        h, ln_g, ln_b, Wq, Wk, Wv, Wo, bias0, mask0, l);
    ffn_kernel<<<dim3(5000), dim3(256), 0, stream>>>(
        h, ln_g, ln_b, ffn_W1, ffn_b1, ffn_W2, ffn_b2, l);
  }
  ego_mlp_kernel<<<dim3(200), dim3(256), 0, stream>>>(h, mlp_W1, mlp_b1,
                                                      mlp_W2, mlp_b2, out);
}

// Round 3
// 810.620 us; speedup vs baseline: 3.6571x; 2.6630x over previous
//
#include <hip/hip_runtime.h>

// Decoder_36996848287748 v3 — bf16 MFMA for all transformer GEMMs.
// N=32 A=50 T=50 D=128 H=8 DH=16 L=2 FF=512 NB=32 OUT_H=512 PRED=60
// Social shortcut: agents i>0 attend only to themselves => out_i = v_i (exact).
// MFMA 16x16x32_bf16 layout: A[m=lane&15][k=(lane>>4)*8+e], B[n=lane&15][k=...],
// C[row=(lane>>4)*4+r][col=lane&15]  (fp32 accum).

#define DD 128
typedef __attribute__((ext_vector_type(8))) short bf16x8;
typedef __attribute__((ext_vector_type(4))) float f32x4;
#define MFMA16(a, b, c) __builtin_amdgcn_mfma_f32_16x16x32_bf16(a, b, c, 0, 0, 0)

__device__ __forceinline__ float bf2f(unsigned short u) {
  union { unsigned int i; float f; } x; x.i = ((unsigned int)u) << 16; return x.f;
}
__device__ __forceinline__ unsigned short f2bf(float f) {
  union { float f; unsigned int i; } x; x.f = f;
  return (unsigned short)((x.i + 0x7FFFu + ((x.i >> 16) & 1u)) >> 16);
}
__device__ __forceinline__ float wave_sum(float v) {
#pragma unroll
  for (int off = 32; off > 0; off >>= 1) v += __shfl_xor(v, off, 64);
  return v;
}
__device__ __forceinline__ float wave_max(float v) {
#pragma unroll
  for (int off = 32; off > 0; off >>= 1) v = fmaxf(v, __shfl_xor(v, off, 64));
  return v;
}
__device__ __forceinline__ bool load_inv(const void* p, int idx, int bytemode) {
  if (bytemode) return ((const unsigned char*)p)[idx] != 0;
  return ((const int*)p)[idx] != 0;
}

__global__ void detect_kernel(const void* __restrict__ inv, int* __restrict__ flag) {
  __shared__ int found;
  if (threadIdx.x == 0) found = 0;
  __syncthreads();
  const unsigned char* p = (const unsigned char*)inv;
  int loc = 0;
  for (int i = threadIdx.x; i < 16384; i += blockDim.x)
    if ((i & 3) != 0 && p[i] != 0) loc = 1;
  if (loc) atomicOr(&found, 1);
  __syncthreads();
  if (threadIdx.x == 0) *flag = found ? 1 : 0;
}

// Transpose+cvt all weights to bf16 [out][in] via 32x32 LDS tiles. 512 blocks.
__global__ __launch_bounds__(256) void convert_weights(
    const float* __restrict__ Wq, const float* __restrict__ Wk,
    const float* __restrict__ Wv, const float* __restrict__ Wo,
    const float* __restrict__ W1, const float* __restrict__ W2,
    unsigned short* __restrict__ wqkv, unsigned short* __restrict__ wot,
    unsigned short* __restrict__ w1t, unsigned short* __restrict__ w2t) {
  __shared__ float tile[32][33];
  int b = blockIdx.x;
  int tx = threadIdx.x & 31, ty = threadIdx.x >> 5;
  const float* src; unsigned short* dst;
  int o0, i0, srcld, dstld, osub = 0;
  if (b < 192) {                       // Wq/Wk/Wv -> wqkv[m][384][128]
    int m = b / 48, t2 = b % 48;
    o0 = (t2 / 4) * 32; i0 = (t2 % 4) * 32;
    int sel = o0 >> 7;
    src = (sel == 0 ? Wq : (sel == 1 ? Wk : Wv)) + m * 16384;
    osub = sel * 128; srcld = 128;
    dst = wqkv + m * 49152; dstld = 128;
  } else if (b < 256) {                // Wo -> wot[m][128][128]
    int m = (b - 192) / 16, t2 = (b - 192) % 16;
    o0 = (t2 / 4) * 32; i0 = (t2 % 4) * 32;
    src = Wo + m * 16384; srcld = 128;
    dst = wot + m * 16384; dstld = 128;
  } else if (b < 384) {                // W1 [128][512] -> w1t[l][512][128]
    int l = (b - 256) / 64, t2 = (b - 256) % 64;
    o0 = (t2 / 4) * 32; i0 = (t2 % 4) * 32;
    src = W1 + l * 65536; srcld = 512;
    dst = w1t + l * 65536; dstld = 128;
  } else {                             // W2 [512][128] -> w2t[l][128][512]
    int l = (b - 384) / 64, t2 = (b - 384) % 64;
    o0 = (t2 / 16) * 32; i0 = (t2 % 16) * 32;
    src = W2 + l * 65536; srcld = 128;
    dst = w2t + l * 65536; dstld = 512;
  }
#pragma unroll
  for (int kk = 0; kk < 4; ++kk) {
    int i = i0 + ty + 8 * kk, o = o0 + tx;
    tile[ty + 8 * kk][tx] = src[i * srcld + (o - osub)];
  }
  __syncthreads();
#pragma unroll
  for (int kk = 0; kk < 4; ++kk) {
    int o = o0 + ty + 8 * kk, i = i0 + tx;
    dst[o * dstld + i] = f2bf(tile[tx][ty + 8 * kk]);
  }
}

// ---------------- Temporal attention (MFMA projections) ----------------
// 512 thr / 8 waves. LDS ~59.5KB -> 2 blocks/CU.
__global__ __launch_bounds__(512, 4) void temporal_attn_kernel(
    const float* __restrict__ x, float* __restrict__ h,
    const void* __restrict__ inv, const int* __restrict__ flagp,
    const float* __restrict__ g, const float* __restrict__ bb,
    const float* __restrict__ embW, const float* __restrict__ embB,
    const unsigned short* __restrict__ wqkv,
    const unsigned short* __restrict__ wot, int first) {
  __shared__ __align__(16) unsigned short xbf[64][136];  // LN out; reused as att
  __shared__ __align__(16) unsigned short qsT[128][58];  // Q transposed
  __shared__ __align__(16) unsigned short ks[50][136];
  __shared__ __align__(16) unsigned short vs[50][136];
  __shared__ unsigned char invs[64];
  int seq = blockIdx.x;
  int tid = threadIdx.x, lane = tid & 63, wid = tid >> 6;
  if (tid < 50) invs[tid] = load_inv(inv, seq * 50 + tid, *flagp) ? 1 : 0;
  // P1: LN (embed fused for layer 0)
  for (int t = wid; t < 50; t += 8) {
    int tok = seq * 50 + t;
    float x0, x1;
    if (first) {
      float c0 = x[tok * 5], c1 = x[tok * 5 + 1], c2 = x[tok * 5 + 2];
      float c3 = x[tok * 5 + 3], c4 = x[tok * 5 + 4];
      x0 = embB[lane] + c0 * embW[lane] + c1 * embW[128 + lane] +
           c2 * embW[256 + lane] + c3 * embW[384 + lane] + c4 * embW[512 + lane];
      x1 = embB[lane + 64] + c0 * embW[lane + 64] + c1 * embW[128 + lane + 64] +
           c2 * embW[256 + lane + 64] + c3 * embW[384 + lane + 64] +
           c4 * embW[512 + lane + 64];
      h[tok * DD + lane] = x0; h[tok * DD + lane + 64] = x1;
    } else {
      x0 = h[tok * DD + lane]; x1 = h[tok * DD + lane + 64];
    }
    float mu = wave_sum(x0 + x1) * (1.0f / 128.0f);
    float d0 = x0 - mu, d1 = x1 - mu;
    float var = wave_sum(d0 * d0 + d1 * d1) * (1.0f / 128.0f);
    float rstd = rsqrtf(var + 1e-5f);
    xbf[t][lane]      = f2bf(d0 * rstd * g[lane] + bb[lane]);
    xbf[t][lane + 64] = f2bf(d1 * rstd * g[lane + 64] + bb[lane + 64]);
  }
  __syncthreads();
  int lrow = lane & 15, lk = (lane >> 4) * 8, lr4 = (lane >> 4) * 4;
  // P2: fused QKV GEMM, M=64(50) N=384 K=128; wave wid owns 48 cols
  {
    f32x4 acc[4][3];
#pragma unroll
    for (int mt = 0; mt < 4; ++mt)
#pragma unroll
      for (int j = 0; j < 3; ++j) acc[mt][j] = (f32x4){0.f, 0.f, 0.f, 0.f};
#pragma unroll
    for (int kt = 0; kt < 4; ++kt) {
      bf16x8 a[4];
#pragma unroll
      for (int mt = 0; mt < 4; ++mt)
        a[mt] = *(const bf16x8*)&xbf[mt * 16 + lrow][kt * 32 + lk];
#pragma unroll
      for (int j = 0; j < 3; ++j) {
        int n = wid * 48 + j * 16 + lrow;
        bf16x8 bfr = *(const bf16x8*)&wqkv[n * 128 + kt * 32 + lk];
#pragma unroll
        for (int mt = 0; mt < 4; ++mt) acc[mt][j] = MFMA16(a[mt], bfr, acc[mt][j]);
      }
    }
#pragma unroll
    for (int mt = 0; mt < 4; ++mt)
#pragma unroll
      for (int j = 0; j < 3; ++j) {
        int n = wid * 48 + j * 16 + lrow;
#pragma unroll
        for (int r = 0; r < 4; ++r) {
          int row = mt * 16 + lr4 + r;
          if (row < 50) {
            unsigned short bv = f2bf(acc[mt][j][r]);
            if (n < 128) qsT[n][row] = bv;
            else if (n < 256) ks[row][n - 128] = bv;
            else vs[row][n - 256] = bv;
          }
        }
      }
  }
  __syncthreads();
  // P3: online-softmax attention core; wave = head, lane = q-row
  {
    int hh = wid, tq = lane;
    if (tq < 50) {
      float q[16], o[16];
      float mx = -1e30f, ssum = 0.f;
#pragma unroll
      for (int u = 0; u < 16; ++u) q[u] = bf2f(qsT[hh * 16 + u][tq]);
      for (int tk = 0; tk < 50; ++tk) {
        bool msk = (tk > tq) || (invs[tk] && tk != tq);
        bf16x8 k0 = *(const bf16x8*)&ks[tk][hh * 16];
        bf16x8 k1 = *(const bf16x8*)&ks[tk][hh * 16 + 8];
        float acc = 0.f;
#pragma unroll
        for (int u = 0; u < 8; ++u)
          acc += q[u] * bf2f((unsigned short)k0[u]) +
                 q[u + 8] * bf2f((unsigned short)k1[u]);
        float s = msk ? -1e9f : acc * 0.25f;
        float nm = fmaxf(mx, s);
        ssum = ssum * __expf(mx - nm) + __expf(s - nm);
        mx = nm;
      }
#pragma unroll
      for (int u = 0; u < 16; ++u) o[u] = 0.f;
      for (int tk = 0; tk < 50; ++tk) {
        bool msk = (tk > tq) || (invs[tk] && tk != tq);
        bf16x8 k0 = *(const bf16x8*)&ks[tk][hh * 16];
        bf16x8 k1 = *(const bf16x8*)&ks[tk][hh * 16 + 8];
        float acc = 0.f;
#pragma unroll
        for (int u = 0; u < 8; ++u)
          acc += q[u] * bf2f((unsigned short)k0[u]) +
                 q[u + 8] * bf2f((unsigned short)k1[u]);
        float s = msk ? -1e9f : acc * 0.25f;
        float p = __expf(s - mx);
        bf16x8 v0 = *(const bf16x8*)&vs[tk][hh * 16];
        bf16x8 v1 = *(const bf16x8*)&vs[tk][hh * 16 + 8];
#pragma unroll
        for (int u = 0; u < 8; ++u) {
          o[u] += p * bf2f((unsigned short)v0[u]);
          o[u + 8] += p * bf2f((unsigned short)v1[u]);
        }
      }
      float rs = 1.f / ssum;
#pragma unroll
      for (int u = 0; u < 16; ++u) xbf[tq][hh * 16 + u] = f2bf(o[u] * rs);
    }
  }
  __syncthreads();
  // P4: Wo + residual; wave wid owns n-tile wid
  {
    f32x4 acc2[4];
#pragma unroll
    for (int mt = 0; mt < 4; ++mt) acc2[mt] = (f32x4){0.f, 0.f, 0.f, 0.f};
#pragma unroll
    for (int kt = 0; kt < 4; ++kt) {
      bf16x8 bfr = *(const bf16x8*)&wot[(wid * 16 + lrow) * 128 + kt * 32 + lk];
#pragma unroll
      for (int mt = 0; mt < 4; ++mt) {
        bf16x8 a = *(const bf16x8*)&xbf[mt * 16 + lrow][kt * 32 + lk];
        acc2[mt] = MFMA16(a, bfr, acc2[mt]);
      }
    }
#pragma unroll
    for (int mt = 0; mt < 4; ++mt)
#pragma unroll
      for (int r = 0; r < 4; ++r) {
        int row = mt * 16 + lr4 + r;
        if (row < 50) h[(seq * 50 + row) * DD + wid * 16 + lrow] += acc2[mt][r];
      }
  }
}

// ---------------- Social attention (MFMA projections) ----------------
// Only agent-0 queries attend; rows i>0 => out_i = v_i. Mask/bias inline.
__global__ __launch_bounds__(512, 4) void social_attn_kernel(
    const float* __restrict__ x, float* __restrict__ h,
    const void* __restrict__ inv, const int* __restrict__ flagp,
    const float* __restrict__ dist_emb,
    const float* __restrict__ g, const float* __restrict__ bb,
    const unsigned short* __restrict__ wqkv,
    const unsigned short* __restrict__ wot) {
  __shared__ __align__(16) unsigned short xbf[64][136];
  __shared__ __align__(16) unsigned short ktT[128][58];
  __shared__ __align__(16) unsigned short vsb[64][136];
  __shared__ float q0s[128];
  __shared__ float aw[8][52];
  int nt_ = blockIdx.x;
  int n = nt_ / 50, t = nt_ - n * 50;
  int tid = threadIdx.x, lane = tid & 63, wid = tid >> 6;
  // P1: LN over strided tokens
  for (int j = wid; j < 50; j += 8) {
    int tok = (n * 50 + j) * 50 + t;
    float x0 = h[tok * DD + lane], x1 = h[tok * DD + lane + 64];
    float mu = wave_sum(x0 + x1) * (1.0f / 128.0f);
    float d0 = x0 - mu, d1 = x1 - mu;
    float var = wave_sum(d0 * d0 + d1 * d1) * (1.0f / 128.0f);
    float rstd = rsqrtf(var + 1e-5f);
    xbf[j][lane]      = f2bf(d0 * rstd * g[lane] + bb[lane]);
    xbf[j][lane + 64] = f2bf(d1 * rstd * g[lane + 64] + bb[lane + 64]);
  }
  __syncthreads();
  int lrow = lane & 15, lk = (lane >> 4) * 8, lr4 = (lane >> 4) * 4;
  // P2: fused QKV GEMM (q kept only for row 0, fp32)
  {
    f32x4 acc[4][3];
#pragma unroll
    for (int mt = 0; mt < 4; ++mt)
#pragma unroll
      for (int j = 0; j < 3; ++j) acc[mt][j] = (f32x4){0.f, 0.f, 0.f, 0.f};
#pragma unroll
    for (int kt = 0; kt < 4; ++kt) {
      bf16x8 a[4];
#pragma unroll
      for (int mt = 0; mt < 4; ++mt)
        a[mt] = *(const bf16x8*)&xbf[mt * 16 + lrow][kt * 32 + lk];
#pragma unroll
      for (int j = 0; j < 3; ++j) {
        int nn = wid * 48 + j * 16 + lrow;
        bf16x8 bfr = *(const bf16x8*)&wqkv[nn * 128 + kt * 32 + lk];
#pragma unroll
        for (int mt = 0; mt < 4; ++mt) acc[mt][j] = MFMA16(a[mt], bfr, acc[mt][j]);
      }
    }
#pragma unroll
    for (int mt = 0; mt < 4; ++mt)
#pragma unroll
      for (int j = 0; j < 3; ++j) {
        int nn = wid * 48 + j * 16 + lrow;
#pragma unroll
        for (int r = 0; r < 4; ++r) {
          int row = mt * 16 + lr4 + r;
          if (nn < 128) {
            if (row == 0) q0s[nn] = acc[mt][j][r];
          } else if (nn < 256) {
            if (row < 50) ktT[nn - 128][row] = f2bf(acc[mt][j][r]);
          } else {
            if (row < 50) vsb[row][nn - 256] = f2bf(acc[mt][j][r]);
          }
        }
      }
  }
  __syncthreads();
  // P3: masked+biased softmax for ego row; wave = head, lane = agent j
  {
    int hh = wid, j = lane;
    float s = -1e30f;
    if (j < 50) {
      float x0 = x[(n * 2500 + t) * 5 + 0];
      float y0 = x[(n * 2500 + t) * 5 + 1];
      int tokj = (n * 50 + j) * 50 + t;
      float xj = x[tokj * 5 + 0], yj = x[tokj * 5 + 1];
      float dx = x0 - xj, dy = y0 - yj;
      float dist = sqrtf(dx * dx + dy * dy);
      int bucket = (int)(dist / 1.5625f);
      bucket = bucket < 0 ? 0 : (bucket > 31 ? 31 : bucket);
      bool mk = (j != 0) && ((dist > 50.0f) || load_inv(inv, tokj, *flagp));
      float acc = 0.f;
#pragma unroll
      for (int u = 0; u < 16; ++u) acc += q0s[hh * 16 + u] * bf2f(ktT[hh * 16 + u][j]);
      s = mk ? -1e9f : acc * 0.25f + dist_emb[bucket * 8 + hh];
    }
    float m = wave_max(s);
    float p = (j < 50) ? __expf(s - m) : 0.f;
    float sm = wave_sum(p);
    if (j < 50) aw[hh][j] = p / sm;
  }
  __syncthreads();
  // P3b: ego attention output -> overwrite vsb row 0
  float a0val = 0.f;
  if (tid < 128) {
    int hh2 = tid >> 4;
    for (int j = 0; j < 50; ++j) a0val += aw[hh2][j] * bf2f(vsb[j][tid]);
  }
  __syncthreads();
  if (tid < 128) vsb[0][tid] = f2bf(a0val);
  __syncthreads();
  // P4: Wo + residual (attn-out rows = vsb)
  {
    f32x4 acc2[4];
#pragma unroll
    for (int mt = 0; mt < 4; ++mt) acc2[mt] = (f32x4){0.f, 0.f, 0.f, 0.f};
#pragma unroll
    for (int kt = 0; kt < 4; ++kt) {
      bf16x8 bfr = *(const bf16x8*)&wot[(wid * 16 + lrow) * 128 + kt * 32 + lk];
#pragma unroll
      for (int mt = 0; mt < 4; ++mt) {
        bf16x8 a = *(const bf16x8*)&vsb[mt * 16 + lrow][kt * 32 + lk];
        acc2[mt] = MFMA16(a, bfr, acc2[mt]);
      }
    }
#pragma unroll
    for (int mt = 0; mt < 4; ++mt)
#pragma unroll
      for (int r = 0; r < 4; ++r) {
        int row = mt * 16 + lr4 + r;
        if (row < 50)
          h[((n * 50 + row) * 50 + t) * DD + wid * 16 + lrow] += acc2[mt][r];
      }
  }
}

// ---------------- FFN (MFMA) ----------------
// 256 thr / 4 waves, 32 tokens/block, LDS 42KB -> 3 blocks/CU.
__global__ __launch_bounds__(256, 3) void ffn_kernel(
    float* __restrict__ h, const float* __restrict__ g, const float* __restrict__ bb,
    const unsigned short* __restrict__ w1t, const float* __restrict__ b1,
    const unsigned short* __restrict__ w2t, const float* __restrict__ b2) {
  __shared__ __align__(16) unsigned short xbf[32][136];
  __shared__ __align__(16) unsigned short hid[32][520];
  int base = blockIdx.x * 32;
  int tid = threadIdx.x, lane = tid & 63, wid = tid >> 6;
  for (int r = wid; r < 32; r += 4) {
    int tok = base + r;
    float x0 = h[tok * DD + lane], x1 = h[tok * DD + lane + 64];
    float mu = wave_sum(x0 + x1) * (1.0f / 128.0f);
    float d0 = x0 - mu, d1 = x1 - mu;
    float var = wave_sum(d0 * d0 + d1 * d1) * (1.0f / 128.0f);
    float rstd = rsqrtf(var + 1e-5f);
    xbf[r][lane]      = f2bf(d0 * rstd * g[lane] + bb[lane]);
    xbf[r][lane + 64] = f2bf(d1 * rstd * g[lane + 64] + bb[lane + 64]);
  }
  __syncthreads();
  int lrow = lane & 15, lk = (lane >> 4) * 8, lr4 = (lane >> 4) * 4;
  // GEMM1: M=32 N=512 K=128; wave wid owns 128 cols
  {
    f32x4 acc[2][8];
#pragma unroll
    for (int mt = 0; mt < 2; ++mt)
#pragma unroll
      for (int nt = 0; nt < 8; ++nt) acc[mt][nt] = (f32x4){0.f, 0.f, 0.f, 0.f};
#pragma unroll
    for (int kt = 0; kt < 4; ++kt) {
      bf16x8 a0 = *(const bf16x8*)&xbf[lrow][kt * 32 + lk];
      bf16x8 a1 = *(const bf16x8*)&xbf[16 + lrow][kt * 32 + lk];
#pragma unroll
      for (int nt = 0; nt < 8; ++nt) {
        int nn = wid * 128 + nt * 16 + lrow;
        bf16x8 bfr = *(const bf16x8*)&w1t[nn * 128 + kt * 32 + lk];
        acc[0][nt] = MFMA16(a0, bfr, acc[0][nt]);
        acc[1][nt] = MFMA16(a1, bfr, acc[1][nt]);
      }
    }
#pragma unroll
    for (int nt = 0; nt < 8; ++nt) {
      int nn = wid * 128 + nt * 16 + lrow;
      float bias = b1[nn];
#pragma unroll
      for (int mt = 0; mt < 2; ++mt)
#pragma unroll
        for (int r = 0; r < 4; ++r)
          hid[mt * 16 + lr4 + r][nn] = f2bf(fmaxf(acc[mt][nt][r] + bias, 0.f));
    }
  }
  __syncthreads();
  // GEMM2: M=32 N=128 K=512; wave wid owns 32 cols
  {
    f32x4 acc2[2][2];
#pragma unroll
    for (int mt = 0; mt < 2; ++mt)
#pragma unroll
      for (int nt = 0; nt < 2; ++nt) acc2[mt][nt] = (f32x4){0.f, 0.f, 0.f, 0.f};
#pragma unroll
    for (int kt = 0; kt < 16; ++kt) {
      bf16x8 a0 = *(const bf16x8*)&hid[lrow][kt * 32 + lk];
      bf16x8 a1 = *(const bf16x8*)&hid[16 + lrow][kt * 32 + lk];
#pragma unroll
      for (int nt = 0; nt < 2; ++nt) {
        int nn = wid * 32 + nt * 16 + lrow;
        bf16x8 bfr = *(const bf16x8*)&w2t[nn * 512 + kt * 32 + lk];
        acc2[0][nt] = MFMA16(a0, bfr, acc2[0][nt]);
        acc2[1][nt] = MFMA16(a1, bfr, acc2[1][nt]);
      }
    }
#pragma unroll
    for (int nt = 0; nt < 2; ++nt) {
      int nn = wid * 32 + nt * 16 + lrow;
      float bias = b2[nn];
#pragma unroll
      for (int mt = 0; mt < 2; ++mt)
#pragma unroll
        for (int r = 0; r < 4; ++r)
          h[(base + mt * 16 + lr4 + r) * DD + nn] += acc2[mt][nt][r] + bias;
    }
  }
}

// Final ego MLP (fp32): e = (h[:,0] @ W1 + b1) @ W2 + b2 -> out (N*T,120)
__global__ __launch_bounds__(256) void ego_mlp_kernel(
    const float* __restrict__ h, const float* __restrict__ W1,
    const float* __restrict__ b1, const float* __restrict__ W2,
    const float* __restrict__ b2, float* __restrict__ out) {
  __shared__ float xr[8][128];
  __shared__ float mid[8][512];
  int base = blockIdx.x * 8;
  int tid = threadIdx.x;
  for (int idx = tid; idx < 1024; idx += 256) {
    int r = idx >> 7, dd = idx & 127;
    int nt = base + r, n = nt / 50, t = nt - n * 50;
    xr[r][dd] = h[(n * 2500 + t) * DD + dd];
  }
  __syncthreads();
  {
    int f = tid;
    float a0[8], a1[8];
#pragma unroll
    for (int r = 0; r < 8; ++r) { a0[r] = b1[f]; a1[r] = b1[f + 256]; }
    for (int c = 0; c < 128; ++c) {
      float w0 = W1[c * 512 + f], w1 = W1[c * 512 + f + 256];
#pragma unroll
      for (int r = 0; r < 8; ++r) {
        float xv = xr[r][c];
        a0[r] += xv * w0;
        a1[r] += xv * w1;
      }
    }
#pragma unroll
    for (int r = 0; r < 8; ++r) { mid[r][f] = a0[r]; mid[r][f + 256] = a1[r]; }
  }
  __syncthreads();
  for (int idx = tid; idx < 960; idx += 256) {
    int r = idx / 120, p = idx - r * 120;
    float acc = b2[p];
    for (int f2 = 0; f2 < 512; ++f2) acc += mid[r][f2] * W2[f2 * 120 + p];
    out[(base + r) * 120 + p] = acc;
  }
}

extern "C" void kernel_launch(void* const* d_in, const int* in_sizes, int n_in,
                              void* d_out, int out_size, void* d_ws, size_t ws_size,
                              hipStream_t stream) {
  const float* x        = (const float*)d_in[0];
  const void*  inv      = d_in[1];
  const float* emb_W    = (const float*)d_in[2];
  const float* emb_b    = (const float*)d_in[3];
  const float* dist_emb = (const float*)d_in[4];
  const float* ln_g     = (const float*)d_in[5];
  const float* ln_b     = (const float*)d_in[6];
  const float* Wq       = (const float*)d_in[7];
  const float* Wk       = (const float*)d_in[8];
  const float* Wv       = (const float*)d_in[9];
  const float* Wo       = (const float*)d_in[10];
  const float* ffn_W1   = (const float*)d_in[11];
  const float* ffn_b1   = (const float*)d_in[12];
  const float* ffn_W2   = (const float*)d_in[13];
  const float* ffn_b2   = (const float*)d_in[14];
  const float* mlp_W1   = (const float*)d_in[15];
  const float* mlp_b1   = (const float*)d_in[16];
  const float* mlp_W2   = (const float*)d_in[17];
  const float* mlp_b2   = (const float*)d_in[18];
  float* out = (float*)d_out;

  float* ws = (float*)d_ws;
  float* h  = ws;                                        // 10,240,000 floats
  unsigned short* wbf = (unsigned short*)(ws + 10240000);
  unsigned short* wqkv = wbf;                            // 4*49152
  unsigned short* wot  = wbf + 196608;                   // 4*16384
  unsigned short* w1t  = wbf + 262144;                   // 2*65536
  unsigned short* w2t  = wbf + 393216;                   // 2*65536
  int* flag = (int*)(ws + 10600000);

  detect_kernel<<<dim3(1), dim3(256), 0, stream>>>(inv, flag);
  convert_weights<<<dim3(512), dim3(256), 0, stream>>>(Wq, Wk, Wv, Wo, ffn_W1,
                                                       ffn_W2, wqkv, wot, w1t, w2t);
  for (int l = 0; l < 2; ++l) {
    temporal_attn_kernel<<<dim3(1600), dim3(512), 0, stream>>>(
        x, h, inv, flag, ln_g + (l * 3 + 0) * DD, ln_b + (l * 3 + 0) * DD,
        emb_W, emb_b, wqkv + (l * 2 + 0) * 49152, wot + (l * 2 + 0) * 16384,
        l == 0 ? 1 : 0);
    social_attn_kernel<<<dim3(1600), dim3(512), 0, stream>>>(
        x, h, inv, flag, dist_emb, ln_g + (l * 3 + 1) * DD,
        ln_b + (l * 3 + 1) * DD, wqkv + (l * 2 + 1) * 49152,
        wot + (l * 2 + 1) * 16384);
    ffn_kernel<<<dim3(2500), dim3(256), 0, stream>>>(
        h, ln_g + (l * 3 + 2) * DD, ln_b + (l * 3 + 2) * DD, w1t + l * 65536,
        ffn_b1 + l * 512, w2t + l * 65536, ffn_b2 + l * 128);
  }
  ego_mlp_kernel<<<dim3(200), dim3(256), 0, stream>>>(h, mlp_W1, mlp_b1,
                                                      mlp_W2, mlp_b2, out);
}